// Round 1
// baseline (5718.944 us; speedup 1.0000x reference)
//
#include <hip/hip_runtime.h>

#define N_NODES 100000
#define DFEAT   128
#define OUTW    384   // 3 * 128

// out[row, 0:128] = feature[row]; out[row, 128:384] = 0
__global__ void init_out_kernel(const float* __restrict__ feat, float* __restrict__ out) {
    int row = blockIdx.x;
    int col = threadIdx.x;            // blockDim.x == 384
    float v = 0.0f;
    if (col < DFEAT) v = feat[row * DFEAT + col];
    out[(long long)row * OUTW + col] = v;
}

__global__ void degree_count_kernel(const int* __restrict__ dst, unsigned int* __restrict__ deg, int E) {
    int e = blockIdx.x * blockDim.x + threadIdx.x;
    if (e < E) atomicAdd(&deg[dst[e]], 1u);
}

__global__ void deg_to_inv_kernel(const unsigned int* __restrict__ deg, float* __restrict__ deg_inv, int n) {
    int i = blockIdx.x * blockDim.x + threadIdx.x;
    if (i < n) {
        unsigned int d = deg[i];
        deg_inv[i] = (d > 0u) ? (1.0f / (float)d) : 0.0f;
    }
}

// One thread per (edge, float4-chunk): 32 chunks cover 128 floats.
// Gathers h_in[src] row (stride in_stride4 float4s), atomic-adds into
// out_base + dst*out_stride + chunk*4.
__global__ void scatter_sum_kernel(const int* __restrict__ src, const int* __restrict__ dst,
                                   const float4* __restrict__ h_in, int in_stride4,
                                   float* __restrict__ out_base, int out_stride, int E) {
    long long idx = (long long)blockIdx.x * blockDim.x + threadIdx.x;
    int e = (int)(idx >> 5);
    int c = (int)(idx & 31);
    if (e >= E) return;
    int s = src[e];
    int d = dst[e];
    float4 v = h_in[(long long)s * in_stride4 + c];
    float* p = out_base + (long long)d * out_stride + c * 4;
#if defined(__HIP_DEVICE_COMPILE__)
    unsafeAtomicAdd(p + 0, v.x);
    unsafeAtomicAdd(p + 1, v.y);
    unsafeAtomicAdd(p + 2, v.z);
    unsafeAtomicAdd(p + 3, v.w);
#else
    atomicAdd(p + 0, v.x);
    atomicAdd(p + 1, v.y);
    atomicAdd(p + 2, v.z);
    atomicAdd(p + 3, v.w);
#endif
}

// Scale 128-wide rows at base (row stride `stride` floats) by deg_inv[row].
__global__ void normalize_kernel(float* __restrict__ base, int stride,
                                 const float* __restrict__ deg_inv, int n) {
    int idx = blockIdx.x * blockDim.x + threadIdx.x;
    int row = idx >> 5;
    int c = idx & 31;
    if (row >= n) return;
    float s = deg_inv[row];
    float4* p = (float4*)(base + (long long)row * stride) + c;
    float4 v = *p;
    v.x *= s; v.y *= s; v.z *= s; v.w *= s;
    *p = v;
}

extern "C" void kernel_launch(void* const* d_in, const int* in_sizes, int n_in,
                              void* d_out, int out_size, void* d_ws, size_t ws_size,
                              hipStream_t stream) {
    const float* feature = (const float*)d_in[0];
    const int* edge_index = (const int*)d_in[1];
    const int E = in_sizes[1] / 2;         // 1,600,000
    const int* src = edge_index;           // edge_index[0, :]
    const int* dst = edge_index + E;       // edge_index[1, :]

    float* out = (float*)d_out;

    // workspace layout: deg (uint, N) | deg_inv (float, N)
    unsigned int* deg = (unsigned int*)d_ws;
    float* deg_inv = (float*)((char*)d_ws + (size_t)N_NODES * sizeof(unsigned int));

    hipMemsetAsync(deg, 0, (size_t)N_NODES * sizeof(unsigned int), stream);

    // out[:,0:128] = feature, out[:,128:384] = 0
    init_out_kernel<<<N_NODES, OUTW, 0, stream>>>(feature, out);

    // in-degree
    degree_count_kernel<<<(E + 255) / 256, 256, 0, stream>>>(dst, deg, E);
    deg_to_inv_kernel<<<(N_NODES + 255) / 256, 256, 0, stream>>>(deg, deg_inv, N_NODES);

    // layer 1: feature -> out[:,128:256] (sum), then normalize
    {
        long long threads = (long long)E * 32;
        int blocks = (int)((threads + 255) / 256);
        scatter_sum_kernel<<<blocks, 256, 0, stream>>>(src, dst,
                                                       (const float4*)feature, DFEAT / 4,
                                                       out + DFEAT, OUTW, E);
        int nthreads = N_NODES * 32;
        normalize_kernel<<<(nthreads + 255) / 256, 256, 0, stream>>>(out + DFEAT, OUTW, deg_inv, N_NODES);
    }

    // layer 2: out[:,128:256] -> out[:,256:384] (sum), then normalize
    {
        long long threads = (long long)E * 32;
        int blocks = (int)((threads + 255) / 256);
        scatter_sum_kernel<<<blocks, 256, 0, stream>>>(src, dst,
                                                       (const float4*)(out + DFEAT), OUTW / 4,
                                                       out + 2 * DFEAT, OUTW, E);
        int nthreads = N_NODES * 32;
        normalize_kernel<<<(nthreads + 255) / 256, 256, 0, stream>>>(out + 2 * DFEAT, OUTW, deg_inv, N_NODES);
    }
}

// Round 2
// 841.652 us; speedup vs baseline: 6.7949x; 6.7949x over previous
//
#include <hip/hip_runtime.h>

#define N_NODES 100000
#define DFEAT   128
#define OUTW    384   // 3 * 128

// out[row, 0:128] = feature[row] (float4 per thread, 32 chunks/row)
__global__ void copy_feat_kernel(const float4* __restrict__ feat4, float* __restrict__ out, int n) {
    int idx = blockIdx.x * blockDim.x + threadIdx.x;
    int row = idx >> 5;
    int c = idx & 31;
    if (row >= n) return;
    float4* out4 = (float4*)(out + (long long)row * OUTW);
    out4[c] = feat4[(long long)row * 32 + c];
}

__global__ void degree_count_kernel(const int* __restrict__ dst, unsigned int* __restrict__ deg, int E) {
    int e = blockIdx.x * blockDim.x + threadIdx.x;
    if (e < E) atomicAdd(&deg[dst[e]], 1u);
}

__global__ void deg_to_inv_kernel(const unsigned int* __restrict__ deg, float* __restrict__ deg_inv, int n) {
    int i = blockIdx.x * blockDim.x + threadIdx.x;
    if (i < n) {
        unsigned int d = deg[i];
        deg_inv[i] = (d > 0u) ? (1.0f / (float)d) : 0.0f;
    }
}

// Single-block exclusive scan over deg[0..n) -> offsets[0..n], cursor = offsets copy.
__global__ __launch_bounds__(1024) void scan_kernel(const unsigned int* __restrict__ deg,
                                                    unsigned int* __restrict__ offsets,
                                                    unsigned int* __restrict__ cursor, int n) {
    __shared__ unsigned int sums[1024];
    int t = threadIdx.x;
    int chunk = (n + 1023) >> 10;
    int lo = t * chunk;
    int hi = lo + chunk; if (hi > n) hi = n; if (lo > n) lo = n;
    unsigned int s = 0;
    for (int i = lo; i < hi; ++i) s += deg[i];
    sums[t] = s;
    __syncthreads();
    // Hillis-Steele inclusive scan over 1024 partials
    for (int d = 1; d < 1024; d <<= 1) {
        unsigned int v = (t >= d) ? sums[t - d] : 0u;
        __syncthreads();
        sums[t] += v;
        __syncthreads();
    }
    unsigned int run = (t > 0) ? sums[t - 1] : 0u;
    for (int i = lo; i < hi; ++i) {
        offsets[i] = run;
        cursor[i] = run;
        run += deg[i];
    }
    if (t == 1023) offsets[n] = sums[1023];
}

// Counting-sort fill: edge_src[ offsets[dst[e]] + k ] = src[e]
__global__ void fill_kernel(const int* __restrict__ src, const int* __restrict__ dst,
                            unsigned int* __restrict__ cursor, int* __restrict__ edge_src, int E) {
    int e = blockIdx.x * blockDim.x + threadIdx.x;
    if (e < E) {
        unsigned int pos = atomicAdd(&cursor[dst[e]], 1u);
        edge_src[pos] = src[e];
    }
}

// One wave (64 lanes) per node: lane l accumulates cols [2l, 2l+1].
// Reads h_in rows (row stride in_stride floats), writes mean into h_out row.
__global__ void gather_mean_kernel(const unsigned int* __restrict__ offsets,
                                   const int* __restrict__ edge_src,
                                   const float* __restrict__ h_in, int in_stride,
                                   float* __restrict__ h_out, int out_stride,
                                   const float* __restrict__ deg_inv, int n) {
    int wave = (blockIdx.x * blockDim.x + threadIdx.x) >> 6;
    int lane = threadIdx.x & 63;
    if (wave >= n) return;
    unsigned int beg = offsets[wave];
    unsigned int end = offsets[wave + 1];
    const float2* hp = (const float2*)h_in;
    int s2 = in_stride >> 1;  // row stride in float2

    float ax = 0.f, ay = 0.f;
    unsigned int k = beg;
    // 2-edge unroll for memory-level parallelism
    for (; k + 2 <= end; k += 2) {
        int s0 = edge_src[k];
        int s1 = edge_src[k + 1];
        float2 v0 = hp[(long long)s0 * s2 + lane];
        float2 v1 = hp[(long long)s1 * s2 + lane];
        ax += v0.x + v1.x;
        ay += v0.y + v1.y;
    }
    if (k < end) {
        int s0 = edge_src[k];
        float2 v0 = hp[(long long)s0 * s2 + lane];
        ax += v0.x;
        ay += v0.y;
    }
    float inv = deg_inv[wave];
    float2* op = (float2*)(h_out + (long long)wave * out_stride);
    float2 r = {ax * inv, ay * inv};
    op[lane] = r;
}

extern "C" void kernel_launch(void* const* d_in, const int* in_sizes, int n_in,
                              void* d_out, int out_size, void* d_ws, size_t ws_size,
                              hipStream_t stream) {
    const float* feature = (const float*)d_in[0];
    const int* edge_index = (const int*)d_in[1];
    const int E = in_sizes[1] / 2;         // 1,600,000
    const int* src = edge_index;           // edge_index[0, :]
    const int* dst = edge_index + E;       // edge_index[1, :]

    float* out = (float*)d_out;

    // workspace layout: deg | deg_inv | offsets(n+1) | cursor | edge_src(E)
    char* ws = (char*)d_ws;
    unsigned int* deg     = (unsigned int*)ws;                 ws += (size_t)N_NODES * 4;
    float*        deg_inv = (float*)ws;                        ws += (size_t)N_NODES * 4;
    unsigned int* offsets = (unsigned int*)ws;                 ws += (size_t)(N_NODES + 1) * 4 + 4; // keep 8B align slack
    unsigned int* cursor  = (unsigned int*)ws;                 ws += (size_t)N_NODES * 4;
    int*          edge_src = (int*)ws;

    hipMemsetAsync(deg, 0, (size_t)N_NODES * sizeof(unsigned int), stream);

    // out[:,0:128] = feature
    {
        int nthreads = N_NODES * 32;
        copy_feat_kernel<<<(nthreads + 255) / 256, 256, 0, stream>>>((const float4*)feature, out, N_NODES);
    }

    // CSR build: degree -> inv, exclusive scan, bucket fill
    degree_count_kernel<<<(E + 255) / 256, 256, 0, stream>>>(dst, deg, E);
    deg_to_inv_kernel<<<(N_NODES + 255) / 256, 256, 0, stream>>>(deg, deg_inv, N_NODES);
    scan_kernel<<<1, 1024, 0, stream>>>(deg, offsets, cursor, N_NODES);
    fill_kernel<<<(E + 255) / 256, 256, 0, stream>>>(src, dst, cursor, edge_src, E);

    // layer 1: feature -> out[:,128:256] (mean over in-edges)
    {
        long long threads = (long long)N_NODES * 64;
        int blocks = (int)((threads + 255) / 256);
        gather_mean_kernel<<<blocks, 256, 0, stream>>>(offsets, edge_src,
                                                       feature, DFEAT,
                                                       out + DFEAT, OUTW,
                                                       deg_inv, N_NODES);
    }

    // layer 2: out[:,128:256] -> out[:,256:384]
    {
        long long threads = (long long)N_NODES * 64;
        int blocks = (int)((threads + 255) / 256);
        gather_mean_kernel<<<blocks, 256, 0, stream>>>(offsets, edge_src,
                                                       out + DFEAT, OUTW,
                                                       out + 2 * DFEAT, OUTW,
                                                       deg_inv, N_NODES);
    }
}

// Round 3
// 609.797 us; speedup vs baseline: 9.3784x; 1.3802x over previous
//
#include <hip/hip_runtime.h>

#define N_NODES   100000
#define DFEAT     128
#define OUTW      384     // 3 * 128
#define SCAN_TILE 1024
#define SCAN_BLOCKS ((N_NODES + SCAN_TILE - 1) / SCAN_TILE)   // 98

// out[row, 0:128] = feature[row] (float4 per thread, 32 chunks/row)
__global__ void copy_feat_kernel(const float4* __restrict__ feat4, float* __restrict__ out, int n) {
    int idx = blockIdx.x * blockDim.x + threadIdx.x;
    int row = idx >> 5;
    int c = idx & 31;
    if (row >= n) return;
    float4* out4 = (float4*)(out + (long long)row * OUTW);
    out4[c] = feat4[(long long)row * 32 + c];
}

__global__ void degree_count_kernel(const int* __restrict__ dst, unsigned int* __restrict__ deg, int E) {
    int e = blockIdx.x * blockDim.x + threadIdx.x;
    if (e < E) atomicAdd(&deg[dst[e]], 1u);
}

// Phase 1: per-tile sums. Block b sums deg[b*1024 .. b*1024+1023] -> partials[b]
__global__ __launch_bounds__(256) void scan_partial_kernel(const unsigned int* __restrict__ deg,
                                                           unsigned int* __restrict__ partials, int n) {
    __shared__ unsigned int red[4];
    int b = blockIdx.x, t = threadIdx.x;
    int i0 = b * SCAN_TILE + t * 4;
    unsigned int s = 0;
    #pragma unroll
    for (int j = 0; j < 4; ++j) {
        int i = i0 + j;
        if (i < n) s += deg[i];
    }
    #pragma unroll
    for (int d = 32; d > 0; d >>= 1) s += __shfl_down(s, d, 64);
    if ((t & 63) == 0) red[t >> 6] = s;
    __syncthreads();
    if (t == 0) partials[b] = red[0] + red[1] + red[2] + red[3];
}

// Phase 2: exclusive scan of the 98 partials (one block, 128 threads)
__global__ __launch_bounds__(128) void scan_base_kernel(const unsigned int* __restrict__ partials,
                                                        unsigned int* __restrict__ bases, int nb) {
    __shared__ unsigned int s[128];
    int t = threadIdx.x;
    s[t] = (t < nb) ? partials[t] : 0u;
    __syncthreads();
    for (int d = 1; d < 128; d <<= 1) {
        unsigned int x = (t >= d) ? s[t - d] : 0u;
        __syncthreads();
        s[t] += x;
        __syncthreads();
    }
    if (t < nb) bases[t] = (t > 0) ? s[t - 1] : 0u;
}

// Phase 3: per-tile rescan. Writes EXCLUSIVE offsets[i] and deg_inv[i].
__global__ __launch_bounds__(256) void scan_tile_kernel(const unsigned int* __restrict__ deg,
                                                        const unsigned int* __restrict__ bases,
                                                        unsigned int* __restrict__ offsets,
                                                        float* __restrict__ deg_inv, int n) {
    __shared__ unsigned int tsum[256];
    int b = blockIdx.x, t = threadIdx.x;
    int i0 = b * SCAN_TILE + t * 4;
    unsigned int v[4];
    unsigned int s = 0;
    #pragma unroll
    for (int j = 0; j < 4; ++j) {
        int i = i0 + j;
        v[j] = (i < n) ? deg[i] : 0u;
        s += v[j];
    }
    tsum[t] = s;
    __syncthreads();
    for (int d = 1; d < 256; d <<= 1) {
        unsigned int x = (t >= d) ? tsum[t - d] : 0u;
        __syncthreads();
        tsum[t] += x;
        __syncthreads();
    }
    unsigned int run = bases[b] + ((t > 0) ? tsum[t - 1] : 0u);
    #pragma unroll
    for (int j = 0; j < 4; ++j) {
        int i = i0 + j;
        if (i < n) {
            offsets[i] = run;
            unsigned int d = v[j];
            deg_inv[i] = (d > 0u) ? (1.0f / (float)d) : 0.0f;
            run += d;
        }
    }
}

// Counting-sort fill; atomically ADVANCES offsets in place. Afterwards
// offsets[i] == exclusive_offsets[i] + deg[i] == exclusive_offsets[i+1],
// so node i's range is [ i>0 ? offsets[i-1] : 0 , offsets[i] ).
__global__ void fill_kernel(const int* __restrict__ src, const int* __restrict__ dst,
                            unsigned int* __restrict__ offsets, int* __restrict__ edge_src, int E) {
    int e = blockIdx.x * blockDim.x + threadIdx.x;
    if (e < E) {
        unsigned int pos = atomicAdd(&offsets[dst[e]], 1u);
        edge_src[pos] = src[e];
    }
}

// One wave per node. Half-wave per edge: lanes 0-31 edge k, lanes 32-63 edge k+1,
// each lane loads one float4 (16B). 4-edge unroll. Halves combined via shfl_xor.
__global__ __launch_bounds__(256) void gather_mean_kernel(const unsigned int* __restrict__ offsets,
                                   const int* __restrict__ edge_src,
                                   const float* __restrict__ h_in, int in_stride,
                                   float* __restrict__ h_out, int out_stride,
                                   const float* __restrict__ deg_inv, int n) {
    int wave = (blockIdx.x * blockDim.x + threadIdx.x) >> 6;
    if (wave >= n) return;
    int lane = threadIdx.x & 63;
    int half = lane >> 5;
    int c = lane & 31;
    unsigned int beg = (wave > 0) ? offsets[wave - 1] : 0u;
    unsigned int end = offsets[wave];
    const float4* hp = (const float4*)h_in;
    int s4 = in_stride >> 2;

    float ax = 0.f, ay = 0.f, az = 0.f, aw = 0.f;
    unsigned int k = beg;
    for (; k + 4 <= end; k += 4) {
        int sA = edge_src[k + half];
        int sB = edge_src[k + 2 + half];
        float4 vA = hp[(long long)sA * s4 + c];
        float4 vB = hp[(long long)sB * s4 + c];
        ax += vA.x + vB.x; ay += vA.y + vB.y; az += vA.z + vB.z; aw += vA.w + vB.w;
    }
    if (k + 2 <= end) {
        int sA = edge_src[k + half];
        float4 vA = hp[(long long)sA * s4 + c];
        ax += vA.x; ay += vA.y; az += vA.z; aw += vA.w;
        k += 2;
    }
    if (k + half < end) {
        int sA = edge_src[k + half];
        float4 vA = hp[(long long)sA * s4 + c];
        ax += vA.x; ay += vA.y; az += vA.z; aw += vA.w;
    }
    ax += __shfl_xor(ax, 32, 64);
    ay += __shfl_xor(ay, 32, 64);
    az += __shfl_xor(az, 32, 64);
    aw += __shfl_xor(aw, 32, 64);
    if (half == 0) {
        float inv = deg_inv[wave];
        float4 r = {ax * inv, ay * inv, az * inv, aw * inv};
        ((float4*)(h_out + (long long)wave * out_stride))[c] = r;
    }
}

extern "C" void kernel_launch(void* const* d_in, const int* in_sizes, int n_in,
                              void* d_out, int out_size, void* d_ws, size_t ws_size,
                              hipStream_t stream) {
    const float* feature = (const float*)d_in[0];
    const int* edge_index = (const int*)d_in[1];
    const int E = in_sizes[1] / 2;         // 1,600,000
    const int* src = edge_index;           // edge_index[0, :]
    const int* dst = edge_index + E;       // edge_index[1, :]

    float* out = (float*)d_out;

    // ws layout: deg | deg_inv | offsets | partials(128) | bases(128) | edge_src(E)
    char* ws = (char*)d_ws;
    unsigned int* deg      = (unsigned int*)ws;  ws += (size_t)N_NODES * 4;
    float*        deg_inv  = (float*)ws;         ws += (size_t)N_NODES * 4;
    unsigned int* offsets  = (unsigned int*)ws;  ws += (size_t)N_NODES * 4;
    unsigned int* partials = (unsigned int*)ws;  ws += 128 * 4;
    unsigned int* bases    = (unsigned int*)ws;  ws += 128 * 4;
    int*          edge_src = (int*)ws;

    hipMemsetAsync(deg, 0, (size_t)N_NODES * sizeof(unsigned int), stream);

    // out[:,0:128] = feature
    {
        int nthreads = N_NODES * 32;
        copy_feat_kernel<<<(nthreads + 255) / 256, 256, 0, stream>>>((const float4*)feature, out, N_NODES);
    }

    // CSR build
    degree_count_kernel<<<(E + 255) / 256, 256, 0, stream>>>(dst, deg, E);
    scan_partial_kernel<<<SCAN_BLOCKS, 256, 0, stream>>>(deg, partials, N_NODES);
    scan_base_kernel<<<1, 128, 0, stream>>>(partials, bases, SCAN_BLOCKS);
    scan_tile_kernel<<<SCAN_BLOCKS, 256, 0, stream>>>(deg, bases, offsets, deg_inv, N_NODES);
    fill_kernel<<<(E + 255) / 256, 256, 0, stream>>>(src, dst, offsets, edge_src, E);

    // layer 1: feature -> out[:,128:256]
    {
        long long threads = (long long)N_NODES * 64;
        int blocks = (int)((threads + 255) / 256);
        gather_mean_kernel<<<blocks, 256, 0, stream>>>(offsets, edge_src,
                                                       feature, DFEAT,
                                                       out + DFEAT, OUTW,
                                                       deg_inv, N_NODES);
    }

    // layer 2: out[:,128:256] -> out[:,256:384]
    {
        long long threads = (long long)N_NODES * 64;
        int blocks = (int)((threads + 255) / 256);
        gather_mean_kernel<<<blocks, 256, 0, stream>>>(offsets, edge_src,
                                                       out + DFEAT, OUTW,
                                                       out + 2 * DFEAT, OUTW,
                                                       deg_inv, N_NODES);
    }
}

// Round 4
// 532.950 us; speedup vs baseline: 10.7307x; 1.1442x over previous
//
#include <hip/hip_runtime.h>

#define N_NODES   100000
#define DFEAT     128
#define OUTW      384     // 3 * 128
#define SCAN_TILE 1024
#define SCAN_BLOCKS ((N_NODES + SCAN_TILE - 1) / SCAN_TILE)   // 98

__device__ inline float bf_lo(unsigned int u) {
    union { unsigned int i; float f; } v; v.i = u << 16; return v.f;
}
__device__ inline float bf_hi(unsigned int u) {
    union { unsigned int i; float f; } v; v.i = u & 0xFFFF0000u; return v.f;
}
__device__ inline unsigned short f2bf(float f) {
    union { float f; unsigned int i; } v; v.f = f;
    unsigned int r = (v.i + 0x7FFFu + ((v.i >> 16) & 1u)) >> 16;  // RNE
    return (unsigned short)r;
}

// out[row,0:128] = feature[row]; featbf[row] = bf16(feature[row])
__global__ void copy_cast_kernel(const float4* __restrict__ feat4, float* __restrict__ out,
                                 ushort4* __restrict__ featbf, int n) {
    int idx = blockIdx.x * blockDim.x + threadIdx.x;
    int row = idx >> 5;
    int c = idx & 31;
    if (row >= n) return;
    float4 v = feat4[(long long)row * 32 + c];
    ((float4*)(out + (long long)row * OUTW))[c] = v;
    ushort4 b; b.x = f2bf(v.x); b.y = f2bf(v.y); b.z = f2bf(v.z); b.w = f2bf(v.w);
    featbf[(long long)row * 32 + c] = b;
}

// fp32-fallback copy (no bf16 table)
__global__ void copy_feat_kernel(const float4* __restrict__ feat4, float* __restrict__ out, int n) {
    int idx = blockIdx.x * blockDim.x + threadIdx.x;
    int row = idx >> 5;
    int c = idx & 31;
    if (row >= n) return;
    ((float4*)(out + (long long)row * OUTW))[c] = feat4[(long long)row * 32 + c];
}

__global__ void degree_count_kernel(const int* __restrict__ dst, unsigned int* __restrict__ deg, int E) {
    int e = blockIdx.x * blockDim.x + threadIdx.x;
    if (e < E) atomicAdd(&deg[dst[e]], 1u);
}

__global__ __launch_bounds__(256) void scan_partial_kernel(const unsigned int* __restrict__ deg,
                                                           unsigned int* __restrict__ partials, int n) {
    __shared__ unsigned int red[4];
    int b = blockIdx.x, t = threadIdx.x;
    int i0 = b * SCAN_TILE + t * 4;
    unsigned int s = 0;
    #pragma unroll
    for (int j = 0; j < 4; ++j) {
        int i = i0 + j;
        if (i < n) s += deg[i];
    }
    #pragma unroll
    for (int d = 32; d > 0; d >>= 1) s += __shfl_down(s, d, 64);
    if ((t & 63) == 0) red[t >> 6] = s;
    __syncthreads();
    if (t == 0) partials[b] = red[0] + red[1] + red[2] + red[3];
}

__global__ __launch_bounds__(128) void scan_base_kernel(const unsigned int* __restrict__ partials,
                                                        unsigned int* __restrict__ bases, int nb) {
    __shared__ unsigned int s[128];
    int t = threadIdx.x;
    s[t] = (t < nb) ? partials[t] : 0u;
    __syncthreads();
    for (int d = 1; d < 128; d <<= 1) {
        unsigned int x = (t >= d) ? s[t - d] : 0u;
        __syncthreads();
        s[t] += x;
        __syncthreads();
    }
    if (t < nb) bases[t] = (t > 0) ? s[t - 1] : 0u;
}

// Writes EXCLUSIVE offsets[i] and deg_inv[i].
__global__ __launch_bounds__(256) void scan_tile_kernel(const unsigned int* __restrict__ deg,
                                                        const unsigned int* __restrict__ bases,
                                                        unsigned int* __restrict__ offsets,
                                                        float* __restrict__ deg_inv, int n) {
    __shared__ unsigned int tsum[256];
    int b = blockIdx.x, t = threadIdx.x;
    int i0 = b * SCAN_TILE + t * 4;
    unsigned int v[4];
    unsigned int s = 0;
    #pragma unroll
    for (int j = 0; j < 4; ++j) {
        int i = i0 + j;
        v[j] = (i < n) ? deg[i] : 0u;
        s += v[j];
    }
    tsum[t] = s;
    __syncthreads();
    for (int d = 1; d < 256; d <<= 1) {
        unsigned int x = (t >= d) ? tsum[t - d] : 0u;
        __syncthreads();
        tsum[t] += x;
        __syncthreads();
    }
    unsigned int run = bases[b] + ((t > 0) ? tsum[t - 1] : 0u);
    #pragma unroll
    for (int j = 0; j < 4; ++j) {
        int i = i0 + j;
        if (i < n) {
            offsets[i] = run;
            unsigned int d = v[j];
            deg_inv[i] = (d > 0u) ? (1.0f / (float)d) : 0.0f;
            run += d;
        }
    }
}

// Counting-sort fill; advances offsets in place. After: node i range is
// [ i>0 ? offsets[i-1] : 0 , offsets[i] ).
__global__ void fill_kernel(const int* __restrict__ src, const int* __restrict__ dst,
                            unsigned int* __restrict__ offsets, int* __restrict__ edge_src, int E) {
    int e = blockIdx.x * blockDim.x + threadIdx.x;
    if (e < E) {
        unsigned int pos = atomicAdd(&offsets[dst[e]], 1u);
        edge_src[pos] = src[e];
    }
}

// bf16-table gather: one wave per node, quarter-wave (16 lanes) per edge.
// Lane loads uint4 = 8 bf16 (16B); row = 256 B. 8 edges in flight in main loop.
// fp32 accumulate; writes fp32 row to h_out (+ optional bf16 row to bf_out).
__global__ __launch_bounds__(256) void gather_mean_bf16_kernel(
        const unsigned int* __restrict__ offsets,
        const int* __restrict__ edge_src,
        const uint4* __restrict__ table,        // bf16 rows, 16 uint4 per row
        float* __restrict__ h_out, int out_stride,
        ushort4* __restrict__ bf_out,           // may be null
        const float* __restrict__ deg_inv, int n) {
    int wave = (blockIdx.x * blockDim.x + threadIdx.x) >> 6;
    if (wave >= n) return;
    int lane = threadIdx.x & 63;
    int sub = lane >> 4;     // 0..3 : which edge of the group of 4
    int c = lane & 15;       // 16B chunk within row
    unsigned int beg = (wave > 0) ? offsets[wave - 1] : 0u;
    unsigned int end = offsets[wave];

    float s0 = 0.f, s1 = 0.f, s2 = 0.f, s3 = 0.f, s4 = 0.f, s5 = 0.f, s6 = 0.f, s7 = 0.f;
    unsigned int k = beg;
    for (; k + 8 <= end; k += 8) {
        int sA = edge_src[k + sub];
        int sB = edge_src[k + 4 + sub];
        uint4 vA = table[(long long)sA * 16 + c];
        uint4 vB = table[(long long)sB * 16 + c];
        s0 += bf_lo(vA.x); s1 += bf_hi(vA.x); s2 += bf_lo(vA.y); s3 += bf_hi(vA.y);
        s4 += bf_lo(vA.z); s5 += bf_hi(vA.z); s6 += bf_lo(vA.w); s7 += bf_hi(vA.w);
        s0 += bf_lo(vB.x); s1 += bf_hi(vB.x); s2 += bf_lo(vB.y); s3 += bf_hi(vB.y);
        s4 += bf_lo(vB.z); s5 += bf_hi(vB.z); s6 += bf_lo(vB.w); s7 += bf_hi(vB.w);
    }
    for (; k < end; k += 4) {
        unsigned int e = k + sub;
        if (e < end) {
            int sA = edge_src[e];
            uint4 vA = table[(long long)sA * 16 + c];
            s0 += bf_lo(vA.x); s1 += bf_hi(vA.x); s2 += bf_lo(vA.y); s3 += bf_hi(vA.y);
            s4 += bf_lo(vA.z); s5 += bf_hi(vA.z); s6 += bf_lo(vA.w); s7 += bf_hi(vA.w);
        }
    }
    // combine the 4 subgroups (lanes c, c+16, c+32, c+48)
    s0 += __shfl_xor(s0, 16, 64); s1 += __shfl_xor(s1, 16, 64);
    s2 += __shfl_xor(s2, 16, 64); s3 += __shfl_xor(s3, 16, 64);
    s4 += __shfl_xor(s4, 16, 64); s5 += __shfl_xor(s5, 16, 64);
    s6 += __shfl_xor(s6, 16, 64); s7 += __shfl_xor(s7, 16, 64);
    s0 += __shfl_xor(s0, 32, 64); s1 += __shfl_xor(s1, 32, 64);
    s2 += __shfl_xor(s2, 32, 64); s3 += __shfl_xor(s3, 32, 64);
    s4 += __shfl_xor(s4, 32, 64); s5 += __shfl_xor(s5, 32, 64);
    s6 += __shfl_xor(s6, 32, 64); s7 += __shfl_xor(s7, 32, 64);
    if (sub == 0) {
        float inv = deg_inv[wave];
        float4 r0 = {s0 * inv, s1 * inv, s2 * inv, s3 * inv};
        float4 r1 = {s4 * inv, s5 * inv, s6 * inv, s7 * inv};
        float4* orow = (float4*)(h_out + (long long)wave * out_stride);
        orow[c * 2]     = r0;
        orow[c * 2 + 1] = r1;
        if (bf_out) {
            ushort4 b0; b0.x = f2bf(r0.x); b0.y = f2bf(r0.y); b0.z = f2bf(r0.z); b0.w = f2bf(r0.w);
            ushort4 b1; b1.x = f2bf(r1.x); b1.y = f2bf(r1.y); b1.z = f2bf(r1.z); b1.w = f2bf(r1.w);
            bf_out[(long long)wave * 32 + c * 2]     = b0;
            bf_out[(long long)wave * 32 + c * 2 + 1] = b1;
        }
    }
}

// fp32 fallback gather (half-wave per edge, float4 per lane)
__global__ __launch_bounds__(256) void gather_mean_kernel(const unsigned int* __restrict__ offsets,
                                   const int* __restrict__ edge_src,
                                   const float* __restrict__ h_in, int in_stride,
                                   float* __restrict__ h_out, int out_stride,
                                   const float* __restrict__ deg_inv, int n) {
    int wave = (blockIdx.x * blockDim.x + threadIdx.x) >> 6;
    if (wave >= n) return;
    int lane = threadIdx.x & 63;
    int half = lane >> 5;
    int c = lane & 31;
    unsigned int beg = (wave > 0) ? offsets[wave - 1] : 0u;
    unsigned int end = offsets[wave];
    const float4* hp = (const float4*)h_in;
    int s4 = in_stride >> 2;

    float ax = 0.f, ay = 0.f, az = 0.f, aw = 0.f;
    unsigned int k = beg;
    for (; k + 4 <= end; k += 4) {
        int sA = edge_src[k + half];
        int sB = edge_src[k + 2 + half];
        float4 vA = hp[(long long)sA * s4 + c];
        float4 vB = hp[(long long)sB * s4 + c];
        ax += vA.x + vB.x; ay += vA.y + vB.y; az += vA.z + vB.z; aw += vA.w + vB.w;
    }
    if (k + 2 <= end) {
        int sA = edge_src[k + half];
        float4 vA = hp[(long long)sA * s4 + c];
        ax += vA.x; ay += vA.y; az += vA.z; aw += vA.w;
        k += 2;
    }
    if (k + half < end) {
        int sA = edge_src[k + half];
        float4 vA = hp[(long long)sA * s4 + c];
        ax += vA.x; ay += vA.y; az += vA.z; aw += vA.w;
    }
    ax += __shfl_xor(ax, 32, 64);
    ay += __shfl_xor(ay, 32, 64);
    az += __shfl_xor(az, 32, 64);
    aw += __shfl_xor(aw, 32, 64);
    if (half == 0) {
        float inv = deg_inv[wave];
        float4 r = {ax * inv, ay * inv, az * inv, aw * inv};
        ((float4*)(h_out + (long long)wave * out_stride))[c] = r;
    }
}

extern "C" void kernel_launch(void* const* d_in, const int* in_sizes, int n_in,
                              void* d_out, int out_size, void* d_ws, size_t ws_size,
                              hipStream_t stream) {
    const float* feature = (const float*)d_in[0];
    const int* edge_index = (const int*)d_in[1];
    const int E = in_sizes[1] / 2;         // 1,600,000
    const int* src = edge_index;           // edge_index[0, :]
    const int* dst = edge_index + E;       // edge_index[1, :]

    float* out = (float*)d_out;

    // ws: deg | deg_inv | offsets | partials(128) | bases(128) | edge_src(E) | featbf | h1bf
    char* ws = (char*)d_ws;
    unsigned int* deg      = (unsigned int*)ws;  ws += (size_t)N_NODES * 4;
    float*        deg_inv  = (float*)ws;         ws += (size_t)N_NODES * 4;
    unsigned int* offsets  = (unsigned int*)ws;  ws += (size_t)N_NODES * 4;
    unsigned int* partials = (unsigned int*)ws;  ws += 128 * 4;
    unsigned int* bases    = (unsigned int*)ws;  ws += 128 * 4;
    int*          edge_src = (int*)ws;           ws += (size_t)E * 4;
    ushort4*      featbf   = (ushort4*)ws;       ws += (size_t)N_NODES * DFEAT * 2;
    ushort4*      h1bf     = (ushort4*)ws;       ws += (size_t)N_NODES * DFEAT * 2;
    size_t need = (size_t)(ws - (char*)d_ws);
    bool use_bf16 = (ws_size >= need);

    hipMemsetAsync(deg, 0, (size_t)N_NODES * sizeof(unsigned int), stream);

    // out[:,0:128] = feature (+ bf16 cast)
    {
        int nthreads = N_NODES * 32;
        if (use_bf16)
            copy_cast_kernel<<<(nthreads + 255) / 256, 256, 0, stream>>>((const float4*)feature, out, featbf, N_NODES);
        else
            copy_feat_kernel<<<(nthreads + 255) / 256, 256, 0, stream>>>((const float4*)feature, out, N_NODES);
    }

    // CSR build
    degree_count_kernel<<<(E + 255) / 256, 256, 0, stream>>>(dst, deg, E);
    scan_partial_kernel<<<SCAN_BLOCKS, 256, 0, stream>>>(deg, partials, N_NODES);
    scan_base_kernel<<<1, 128, 0, stream>>>(partials, bases, SCAN_BLOCKS);
    scan_tile_kernel<<<SCAN_BLOCKS, 256, 0, stream>>>(deg, bases, offsets, deg_inv, N_NODES);
    fill_kernel<<<(E + 255) / 256, 256, 0, stream>>>(src, dst, offsets, edge_src, E);

    long long threads = (long long)N_NODES * 64;
    int blocks = (int)((threads + 255) / 256);
    if (use_bf16) {
        // layer 1: featbf -> out[:,128:256] (+ h1bf)
        gather_mean_bf16_kernel<<<blocks, 256, 0, stream>>>(offsets, edge_src,
                                                            (const uint4*)featbf,
                                                            out + DFEAT, OUTW,
                                                            h1bf, deg_inv, N_NODES);
        // layer 2: h1bf -> out[:,256:384]
        gather_mean_bf16_kernel<<<blocks, 256, 0, stream>>>(offsets, edge_src,
                                                            (const uint4*)h1bf,
                                                            out + 2 * DFEAT, OUTW,
                                                            (ushort4*)nullptr, deg_inv, N_NODES);
    } else {
        gather_mean_kernel<<<blocks, 256, 0, stream>>>(offsets, edge_src,
                                                       feature, DFEAT,
                                                       out + DFEAT, OUTW,
                                                       deg_inv, N_NODES);
        gather_mean_kernel<<<blocks, 256, 0, stream>>>(offsets, edge_src,
                                                       out + DFEAT, OUTW,
                                                       out + 2 * DFEAT, OUTW,
                                                       deg_inv, N_NODES);
    }
}